// Round 1
// 57.352 us; speedup vs baseline: 1.0109x; 1.0109x over previous
//
#include <hip/hip_runtime.h>

// B=16, K=4, NQ=10, DIM=1024. U = Rx(w0) ⊗ ... ⊗ Rx(w9) @ real state.
// Gate q acts on amplitude-index bit p = NQ-1-q (gate 0 = kron MSB).
//
// This version: ONE WAVE (64 lanes) per bk, 16 amplitudes per lane held
// entirely in registers. Amplitude index decomposition:
//   amp = g*256 + lane*4 + rlo   (r = g*4 + rlo, g in [0,4), rlo in [0,4))
//   bits [9:8] = g (reg bits 3:2), [7:2] = lane, [1:0] = rlo (reg bits 1:0)
// Gates on register bits  -> pure-register butterflies (no communication).
// Gates on lane bits      -> __shfl_xor (wave64, no LDS, no barriers).
// The Rx butterfly is symmetric for both halves:
//   re' = a*re + b*im_partner ; im' = a*im - b*re_partner
// so shuffle gates need no "which half am I" branch.
//
// Output complex64 as PLANAR (all re, then all im) when out_size >= 2*BK*DIM
// (validated by the previous session's passing run); real-only otherwise.

constexpr int BK  = 16 * 4;
constexpr int NQ  = 10;
constexpr int DIM = 1 << NQ;  // 1024

__global__ __launch_bounds__(64)
void rx_layer_kernel(const float* __restrict__ weights,  // (BK, NQ)
                     const float* __restrict__ state,    // (BK, DIM) real
                     float* __restrict__ out_re,         // (BK, DIM)
                     float* __restrict__ out_im)         // (BK, DIM) or nullptr
{
    const int bk   = blockIdx.x;
    const int lane = threadIdx.x;  // 0..63

    float re[16], im[16];
    const float4* st4 = reinterpret_cast<const float4*>(state + bk * DIM);
    #pragma unroll
    for (int g = 0; g < 4; ++g) {
        const float4 v = st4[g * 64 + lane];
        re[g * 4 + 0] = v.x; re[g * 4 + 1] = v.y;
        re[g * 4 + 2] = v.z; re[g * 4 + 3] = v.w;
        im[g * 4 + 0] = 0.0f; im[g * 4 + 1] = 0.0f;
        im[g * 4 + 2] = 0.0f; im[g * 4 + 3] = 0.0f;
    }

    const float* w = weights + bk * NQ;

    #pragma unroll
    for (int q = 0; q < NQ; ++q) {
        const float wv = w[q];             // wave-uniform (scalar load)
        const float a  = cosf(0.5f * wv);
        const float b  = sinf(0.5f * wv);
        const int   p  = NQ - 1 - q;       // amplitude bit this gate acts on

        if (p >= 2 && p <= 7) {
            // Lane bit (p-2): exchange partner values via shfl_xor.
            const int lmask = 1 << (p - 2);
            #pragma unroll
            for (int r = 0; r < 16; ++r) {
                const float pr = __shfl_xor(re[r], lmask);
                const float pi = __shfl_xor(im[r], lmask);
                re[r] = a * re[r] + b * pi;
                im[r] = a * im[r] - b * pr;
            }
        } else {
            // Register bit: p==9 -> bit3 (m=8), p==8 -> bit2 (m=4),
            //               p==1 -> bit1 (m=2), p==0 -> bit0 (m=1)
            const int m = (p >= 8) ? (1 << (p - 6)) : (1 << p);
            #pragma unroll
            for (int r0 = 0; r0 < 16; ++r0) {
                if (r0 & m) continue;
                const int r1 = r0 | m;
                const float x0r = re[r0], x0i = im[r0];
                const float x1r = re[r1], x1i = im[r1];
                re[r0] = a * x0r + b * x1i;
                im[r0] = a * x0i - b * x1r;
                re[r1] = a * x1r + b * x0i;
                im[r1] = a * x1i - b * x0r;
            }
        }
    }

    float4* or4 = reinterpret_cast<float4*>(out_re + bk * DIM);
    #pragma unroll
    for (int g = 0; g < 4; ++g)
        or4[g * 64 + lane] =
            make_float4(re[g*4+0], re[g*4+1], re[g*4+2], re[g*4+3]);
    if (out_im != nullptr) {
        float4* oi4 = reinterpret_cast<float4*>(out_im + bk * DIM);
        #pragma unroll
        for (int g = 0; g < 4; ++g)
            oi4[g * 64 + lane] =
                make_float4(im[g*4+0], im[g*4+1], im[g*4+2], im[g*4+3]);
    }
}

extern "C" void kernel_launch(void* const* d_in, const int* in_sizes, int n_in,
                              void* d_out, int out_size, void* d_ws, size_t ws_size,
                              hipStream_t stream) {
    const float* weights = (const float*)d_in[0];  // 640 floats
    const float* state   = (const float*)d_in[1];  // 65536 floats
    float* out = (float*)d_out;

    float* out_re = out;
    float* out_im = nullptr;
    if (out_size >= 2 * BK * DIM) {
        // planar complex: [all real][all imag]
        out_im = out + BK * DIM;
    }
    rx_layer_kernel<<<BK, 64, 0, stream>>>(weights, state, out_re, out_im);
}